// Round 7
// baseline (277.521 us; speedup 1.0000x reference)
//
#include <hip/hip_runtime.h>
#include <math.h>

#define BLOCK 512
#define MSTR 209   // mags row stride (f32): 209%32=17, odd -> conflict-free lane-major reads

typedef __attribute__((ext_vector_type(8))) short short8;
typedef __attribute__((ext_vector_type(16))) float f32x16;
typedef __attribute__((ext_vector_type(8))) float f32x8;

__device__ inline unsigned short f2bf(float x) {
    unsigned u = __float_as_uint(x);
    unsigned r = u + 0x7fffu + ((u >> 16) & 1u);
    return (unsigned short)(r >> 16);
}

struct ASplit { short8 h, l; };

// split 8 f32 (by value) into hi/lo bf16 fragments — pure register code
__device__ inline ASplit splitA(f32x8 v) {
    unsigned ah[4], al[4];
    #pragma unroll
    for (int q = 0; q < 4; ++q) {
        unsigned short h0 = f2bf(v[2*q]),   h1 = f2bf(v[2*q+1]);
        float hf0 = __uint_as_float((unsigned)h0 << 16);
        float hf1 = __uint_as_float((unsigned)h1 << 16);
        unsigned short l0 = f2bf(v[2*q] - hf0), l1 = f2bf(v[2*q+1] - hf1);
        ah[q] = (unsigned)h0 | ((unsigned)h1 << 16);
        al[q] = (unsigned)l0 | ((unsigned)l1 << 16);
    }
    ASplit r;
    r.h = __builtin_bit_cast(short8, *(uint4*)ah);
    r.l = __builtin_bit_cast(short8, *(uint4*)al);
    return r;
}

// load 8 consecutive floats at absolute padded offset i0; reflect on edges
__device__ inline f32x8 loadA8(const float* __restrict__ x, int i0) {
    f32x8 r;
    if (i0 >= 0 && i0 <= 15992) {
        float4 a0 = *(const float4*)(x + i0);
        float4 a1 = *(const float4*)(x + i0 + 4);
        r[0] = a0.x; r[1] = a0.y; r[2] = a0.z; r[3] = a0.w;
        r[4] = a1.x; r[5] = a1.y; r[6] = a1.z; r[7] = a1.w;
    } else {
        #pragma unroll
        for (int e = 0; e < 8; ++e) {
            int p = i0 + e;
            p = (p < 0) ? -p : p;
            p = (p > 15999) ? (31998 - p) : p;
            r[e] = x[p];
        }
    }
    return r;
}

// ---------------------------------------------------------------------------
// Kernel 1: filters output (64 x 201) -> tail of d_out. Mirrors _get_filters.
// ---------------------------------------------------------------------------
__global__ void fse_filters(const float* __restrict__ low_hz_,
                            const float* __restrict__ band_hz_,
                            float* __restrict__ out)
{
    int idx = blockIdx.x * 256 + threadIdx.x;
    if (idx >= 64 * 201) return;
    int c = idx / 201;
    int k = idx - c * 201;
    float lo = 50.0f + fabsf(low_hz_[c]);
    float hi = lo + 50.0f + fabsf(band_hz_[c]);
    hi = fminf(fmaxf(hi, 50.0f), 8000.0f);
    float ctr = 0.5f * (lo + hi);
    float hbw = 0.5f * (hi - lo);
    float fq = 40.0f * (float)k;
    float resp = 1.0f - fabsf(fq - ctr) / hbw;
    out[idx] = (fq >= lo && fq <= hi) ? resp : 0.0f;
}

// ---------------------------------------------------------------------------
// Kernel 1b: B in chunk-linear layout: Bt[kc][pl][part][row][8] bf16 (hi/lo).
//   row j: j<=200 -> re bin j ; 224<=j<=424 -> im bin j-224 ; else 0.
//   Fragment reads are lane-consecutive 16B -> perfectly coalesced global.
// ---------------------------------------------------------------------------
__global__ void fse_setup_B(unsigned short* __restrict__ bt)
{
    int idx = blockIdx.x * 256 + threadIdx.x;   // 13*2*4*448*8 = 372736
    if (idx >= 372736) return;
    int e   = idx & 7;
    int t   = idx >> 3;
    int row = t % 448;
    int q   = t / 448;          // ((kc*2 + pl)*4 + p)
    int p   = q & 3;
    int pl  = (q >> 2) & 1;
    int kc  = q >> 3;
    int n   = kc * 32 + p * 8 + e;
    float v = 0.0f;
    if (n < 400) {
        int bin = -1, isim = 0;
        if (row <= 200) bin = row;
        else if (row >= 224 && row <= 424) { bin = row - 224; isim = 1; }
        if (bin >= 0) {
            int a = (bin * n) % 400;            // exact integer phase reduction
            float th = 6.283185307179586f * ((float)a / 400.0f);
            float sn, cs;
            sincosf(th, &sn, &cs);
            float wn = 0.5f - 0.5f * cosf(6.283185307179586f * ((float)n / 400.0f));
            v = isim ? (-wn * sn) : (wn * cs);
        }
    }
    unsigned short h = f2bf(v);
    float hf = __uint_as_float((unsigned)h << 16);
    unsigned short l = f2bf(v - hf);
    bt[idx] = pl ? l : h;
}

// ---------------------------------------------------------------------------
// Kernel 2 (MFMA path): one block per batch item.
//  C[128 x 448] = A[128 x 416] x B[416 x 448], split-2 bf16 (3 products).
//  R7: NO LDS / NO barriers in the K-loop. B fragments read directly from
//  global (L1/L2-resident, coalesced); A per-lane from global. 8 waves =
//  2 m-groups (2 m-tiles each) x 4 n-groups ({4,4,3,3} col-tiles) -> each
//  B fragment serves 6 MFMAs (2 m-tiles x 3 products), half the duplication.
//  C layout (HW-verified m74): col = lane&31, row = (r&3)+8*(r>>2)+4*(lane>>5).
// ---------------------------------------------------------------------------
__global__ __launch_bounds__(512, 2)
void fse_main_mfma(const float* __restrict__ wav,
                   const float* __restrict__ low_hz_,
                   const float* __restrict__ band_hz_,
                   const float* __restrict__ ln_w,
                   const float* __restrict__ ln_b,
                   const unsigned short* __restrict__ Bt,
                   float* __restrict__ out)
{
    __shared__ float mags[101 * MSTR];   // 84436 B
    __shared__ float fbuf[64 * 101];
    __shared__ float fctr[64], finv[64];
    __shared__ int   fks[64], fke[64];
    __shared__ float red[16];
    __shared__ float stats[2];

    const int b    = blockIdx.x;
    const int tid  = threadIdx.x;
    const int w    = tid >> 6;
    const int lane = tid & 63;
    const float* __restrict__ x = wav + b * 16000;

    // ---- per-channel filter params (read after the epilogue barriers)
    if (tid < 64) {
        float lo = 50.0f + fabsf(low_hz_[tid]);
        float hi = lo + 50.0f + fabsf(band_hz_[tid]);
        hi = fminf(fmaxf(hi, 50.0f), 8000.0f);
        float ctr = 0.5f * (lo + hi);
        float hbw = 0.5f * (hi - lo);
        int ks = (int)ceilf(lo * 0.025f);
        if (ks < 0) ks = 0;
        while (40.0f * (float)ks < lo) ++ks;
        while (ks > 0 && 40.0f * (float)(ks - 1) >= lo) --ks;
        int ke = (int)floorf(hi * 0.025f);
        if (ke > 200) ke = 200;
        while (40.0f * (float)ke > hi) --ke;
        while (ke < 200 && 40.0f * (float)(ke + 1) <= hi) ++ke;
        fctr[tid] = ctr;
        finv[tid] = (hbw > 0.0f) ? (1.0f / hbw) : 0.0f;
        fks[tid]  = ks;
        fke[tid]  = ke;
    }

    const int mg    = w >> 2;          // m-group: rows 64*mg .. 64*mg+63
    const int nq    = w & 3;           // n-group
    const int nbase = (nq < 3) ? nq * 4 : 11;   // {0,4,8,11}
    const int cnt   = (nq < 2) ? 4 : 3;         // {4,4,3,3} -> covers nt 0..13
    const int jrow  = lane & 31;
    const int g     = lane >> 5;

    const int arow0 = 64 * mg + jrow;
    const int arow1 = 64 * mg + 32 + jrow;
    const int te0   = (arow0 <= 100) ? arow0 : 50;
    const int te1   = (arow1 <= 100) ? arow1 : 50;
    const int ab0   = 160 * te0 - 200 + g * 8;
    const int ab1   = 160 * te1 - 200 + g * 8;

    f32x16 accA[4], accB[4];           // [n] for m-tile 0 / 1
    #pragma unroll
    for (int n = 0; n < 4; ++n) {
        #pragma unroll
        for (int e = 0; e < 16; ++e) { accA[n][e] = 0.0f; accB[n][e] = 0.0f; }
    }

    // ---- K loop: barrier-free, B direct from global (L1/L2)
    for (int kc = 0; kc < 13; ++kc) {
        // A for this kc (value-semantic; reflect on edge rows)
        f32x8 a00 = loadA8(x, ab0 + kc * 32);
        f32x8 a01 = loadA8(x, ab0 + kc * 32 + 16);
        f32x8 a10 = loadA8(x, ab1 + kc * 32);
        f32x8 a11 = loadA8(x, ab1 + kc * 32 + 16);
        ASplit A00 = splitA(a00);   // mtl0, s0
        ASplit A01 = splitA(a01);   // mtl0, s1
        ASplit A10 = splitA(a10);   // mtl1, s0
        ASplit A11 = splitA(a11);   // mtl1, s1

        #pragma unroll
        for (int s = 0; s < 2; ++s) {
            const short8 Ah0 = s ? A01.h : A00.h;
            const short8 Al0 = s ? A01.l : A00.l;
            const short8 Ah1 = s ? A11.h : A10.h;
            const short8 Al1 = s ? A11.l : A10.l;
            const int part = s * 2 + g;
            // base (in shorts) of Bt[kc][pl][part][.]
            const int bh = ((kc * 2 + 0) * 4 + part) * 3584;
            const int bl = ((kc * 2 + 1) * 4 + part) * 3584;
            #pragma unroll
            for (int n = 0; n < 4; ++n) {
                if (n < cnt) {
                    const int ro = (nbase + n) * 32 + jrow;
                    short8 Bh = *(const short8*)(Bt + bh + ro * 8);
                    short8 Bl = *(const short8*)(Bt + bl + ro * 8);
                    accA[n] = __builtin_amdgcn_mfma_f32_32x32x16_bf16(Ah0, Bh, accA[n], 0, 0, 0);
                    accA[n] = __builtin_amdgcn_mfma_f32_32x32x16_bf16(Ah0, Bl, accA[n], 0, 0, 0);
                    accA[n] = __builtin_amdgcn_mfma_f32_32x32x16_bf16(Al0, Bh, accA[n], 0, 0, 0);
                    accB[n] = __builtin_amdgcn_mfma_f32_32x32x16_bf16(Ah1, Bh, accB[n], 0, 0, 0);
                    accB[n] = __builtin_amdgcn_mfma_f32_32x32x16_bf16(Ah1, Bl, accB[n], 0, 0, 0);
                    accB[n] = __builtin_amdgcn_mfma_f32_32x32x16_bf16(Al1, Bh, accB[n], 0, 0, 0);
                }
            }
        }
    }

    // ---- epilogue phase 1: write all RE tiles (nt < 7) to mags
    #pragma unroll
    for (int n = 0; n < 4; ++n) {
        if (n < cnt) {
            const int nt = nbase + n;
            if (nt < 7) {
                const int k = nt * 32 + jrow;
                if (k <= 200) {
                    #pragma unroll
                    for (int r = 0; r < 16; ++r) {
                        int t = 64 * mg + (r & 3) + 8 * (r >> 2) + 4 * g;
                        if (t <= 100)      mags[t * MSTR + k]        = accA[n][r];
                        if (t + 32 <= 100) mags[(t + 32) * MSTR + k] = accB[n][r];
                    }
                }
            }
        }
    }
    __syncthreads();
    // ---- epilogue phase 2: fold IM tiles (7 <= nt < 14) into magnitude
    #pragma unroll
    for (int n = 0; n < 4; ++n) {
        if (n < cnt) {
            const int nt = nbase + n;
            if (nt >= 7 && nt < 14) {
                const int k = (nt - 7) * 32 + jrow;
                if (k <= 200) {
                    #pragma unroll
                    for (int r = 0; r < 16; ++r) {
                        int t = 64 * mg + (r & 3) + 8 * (r >> 2) + 4 * g;
                        if (t <= 100) {
                            float re = mags[t * MSTR + k];
                            float im = accA[n][r];
                            mags[t * MSTR + k] = sqrtf(re * re + im * im);
                        }
                        if (t + 32 <= 100) {
                            float re = mags[(t + 32) * MSTR + k];
                            float im = accB[n][r];
                            mags[(t + 32) * MSTR + k] = sqrtf(re * re + im * im);
                        }
                    }
                }
            }
        }
    }
    __syncthreads();

    // ---- filterbank: lane = t (wave-uniform k-loop, conflict-free reads)
    {
        const int t0 = lane;
        const int t1v = 64 + lane;
        const int t1 = (t1v <= 100) ? t1v : 100;   // clamped read, guarded store
        #pragma unroll
        for (int i = 0; i < 8; ++i) {
            const int c = w * 8 + i;
            const float ctr = fctr[c];
            const float inv = finv[c];
            const int ks = fks[c], ke = fke[c];
            float a0 = 0.0f, a1 = 0.0f;
            for (int k = ks; k <= ke; ++k) {
                float resp = 1.0f - fabsf(40.0f * (float)k - ctr) * inv;
                a0 = fmaf(resp, mags[t0 * MSTR + k], a0);
                a1 = fmaf(resp, mags[t1 * MSTR + k], a1);
            }
            fbuf[c * 101 + t0] = a0;
            if (t1v <= 100) fbuf[c * 101 + t1v] = a1;
        }
    }
    __syncthreads();

    // ---- global LayerNorm (one-pass: sum + sumsq)
    float s = 0.0f, ss = 0.0f;
    for (int i = tid; i < 6464; i += BLOCK) {
        float vv = fbuf[i];
        s += vv;
        ss = fmaf(vv, vv, ss);
    }
    #pragma unroll
    for (int off = 32; off > 0; off >>= 1) {
        s  += __shfl_down(s,  off, 64);
        ss += __shfl_down(ss, off, 64);
    }
    if (lane == 0) { red[w] = s; red[8 + w] = ss; }
    __syncthreads();
    if (tid == 0) {
        float ts = 0.0f, tss = 0.0f;
        for (int i = 0; i < 8; ++i) { ts += red[i]; tss += red[8 + i]; }
        float mu = ts * (1.0f / 6464.0f);
        stats[0] = mu;
        stats[1] = tss * (1.0f / 6464.0f) - mu * mu;
    }
    __syncthreads();
    const float mu   = stats[0];
    const float isig = 1.0f / sqrtf(stats[1] + 1e-5f);

    // ---- log-energy + interp 101->64 + transposed store
    for (int idx = tid; idx < 4096; idx += BLOCK) {
        const int to = idx >> 6;
        const int c  = idx & 63;
        float pos = ((float)to + 0.5f) * 1.578125f - 0.5f;
        pos = fminf(fmaxf(pos, 0.0f), 100.0f);
        int i0 = (int)floorf(pos);
        int i1 = i0 + 1; if (i1 > 100) i1 = 100;
        float fr = pos - (float)i0;
        float wc = ln_w[c], bc = ln_b[c];
        float x0 = fbuf[c * 101 + i0];
        float x1 = fbuf[c * 101 + i1];
        float y0 = fmaf(wc, (x0 - mu) * isig, bc);
        float y1 = fmaf(wc, (x1 - mu) * isig, bc);
        float l0 = log10f(fmaf(y0, y0, 1e-6f));
        float l1 = log10f(fmaf(y1, y1, 1e-6f));
        out[b * 4096 + idx] = l0 * (1.0f - fr) + l1 * fr;
    }
}

// ---------------------------------------------------------------------------
// Fallback (R2 VALU path) if ws_size is too small for the B table.
// ---------------------------------------------------------------------------
__global__ __launch_bounds__(512, 2)
void fse_main_valu(const float* __restrict__ wav,
                   const float* __restrict__ low_hz_,
                   const float* __restrict__ band_hz_,
                   const float* __restrict__ ln_w,
                   const float* __restrict__ ln_b,
                   float* __restrict__ out)
{
    __shared__ float  xp[16400];
    __shared__ float2 Xs[8][204];
    __shared__ float  mags[8][204];
    __shared__ float  fbuf[64 * 101];
    __shared__ float  fctr[64], finv[64];
    __shared__ int    fks[64], fke[64];
    __shared__ float  red[8];
    __shared__ float  stats[2];

    const int b    = blockIdx.x;
    const int tid  = threadIdx.x;
    const int w    = tid >> 6;
    const int lane = tid & 63;
    const float* __restrict__ x = wav + b * 16000;

    for (int i = tid; i < 16400; i += BLOCK) {
        int p = i - 200;
        p = (p < 0) ? -p : p;
        p = (p > 15999) ? (31998 - p) : p;
        xp[i] = x[p];
    }
    if (tid < 64) {
        float lo = 50.0f + fabsf(low_hz_[tid]);
        float hi = lo + 50.0f + fabsf(band_hz_[tid]);
        hi = fminf(fmaxf(hi, 50.0f), 8000.0f);
        float ctr = 0.5f * (lo + hi);
        float hbw = 0.5f * (hi - lo);
        int ks = (int)ceilf(lo * 0.025f);
        if (ks < 0) ks = 0;
        while (40.0f * (float)ks < lo) ++ks;
        while (ks > 0 && 40.0f * (float)(ks - 1) >= lo) --ks;
        int ke = (int)floorf(hi * 0.025f);
        if (ke > 200) ke = 200;
        while (40.0f * (float)ke > hi) --ke;
        while (ke < 200 && 40.0f * (float)(ke + 1) <= hi) ++ke;
        fctr[tid] = ctr;
        finv[tid] = (hbw > 0.0f) ? (1.0f / hbw) : 0.0f;
        fks[tid]  = ks;
        fke[tid]  = ke;
    }
    __syncthreads();

    const float cctr = fctr[lane];
    const float cinv = finv[lane];
    const int   cks  = fks[lane];
    const int   cke  = fke[lane];

    float reX[4][13], imX[4][13];
    const float2* __restrict__ xp2 = (const float2*)xp;
    float c0[4], s0[4], c1[4], s1[4], cd[4], sd[4];
    #pragma unroll
    for (int m = 0; m < 4; ++m) {
        const int k = m * 64 + lane;
        const float th = -0.015707963267948966f * (float)k;
        sincosf(th, &s1[m], &c1[m]);
        sincosf(th + th, &sd[m], &cd[m]);
        c0[m] = 1.0f; s0[m] = 0.0f;
        #pragma unroll
        for (int j = 0; j < 13; ++j) { reX[m][j] = 0.0f; imX[m][j] = 0.0f; }
    }
    const int o12 = (w < 5) ? 640 * 12 : 0;
    int ib = 80 * w;
    #pragma unroll 2
    for (int h = 0; h < 200; ++h) {
        #pragma unroll
        for (int j = 0; j < 13; ++j) {
            const int off = (j == 12) ? o12 : 640 * j;
            float2 f = xp2[ib + off];
            #pragma unroll
            for (int m = 0; m < 4; ++m) {
                reX[m][j] = fmaf(f.x, c0[m], reX[m][j]);
                imX[m][j] = fmaf(f.x, s0[m], imX[m][j]);
                reX[m][j] = fmaf(f.y, c1[m], reX[m][j]);
                imX[m][j] = fmaf(f.y, s1[m], imX[m][j]);
            }
        }
        #pragma unroll
        for (int m = 0; m < 4; ++m) {
            float nc0 = fmaf(c0[m], cd[m], -(s0[m] * sd[m]));
            float ns0 = fmaf(s0[m], cd[m],  (c0[m] * sd[m]));
            float nc1 = fmaf(c1[m], cd[m], -(s1[m] * sd[m]));
            float ns1 = fmaf(s1[m], cd[m],  (c1[m] * sd[m]));
            c0[m] = nc0; s0[m] = ns0; c1[m] = nc1; s1[m] = ns1;
        }
        ++ib;
    }

    float2* __restrict__ myX   = &Xs[w][0];
    float*  __restrict__ mymag = &mags[w][0];
    for (int j = 0; j < 13; ++j) {
        const int t = w + 8 * j;
        if (t > 100) break;
        #pragma unroll
        for (int m = 0; m < 4; ++m) {
            const int k = m * 64 + lane;
            if (k < 202) myX[k] = make_float2(reX[m][j], imX[m][j]);
        }
        asm volatile("s_waitcnt lgkmcnt(0)" ::: "memory");
        #pragma unroll
        for (int m = 0; m < 4; ++m) {
            const int k = m * 64 + lane;
            if (k <= 200) {
                float2 xm = (k == 0) ? myX[1] : myX[k - 1];
                float imm = (k == 0) ? -xm.y : xm.y;
                float2 xq = myX[k + 1];
                float rw = 0.5f * reX[m][j] - 0.25f * (xm.x + xq.x);
                float iw = 0.5f * imX[m][j] - 0.25f * (imm  + xq.y);
                mymag[k] = sqrtf(rw * rw + iw * iw);
            }
        }
        asm volatile("s_waitcnt lgkmcnt(0)" ::: "memory");
        float acc = 0.0f;
        for (int k = cks; k <= cke; ++k) {
            float resp = 1.0f - fabsf(40.0f * (float)k - cctr) * cinv;
            acc = fmaf(resp, mymag[k], acc);
        }
        fbuf[lane * 101 + t] = acc;
    }
    __syncthreads();

    float s = 0.0f;
    for (int i = tid; i < 6464; i += BLOCK) s += fbuf[i];
    #pragma unroll
    for (int off = 32; off > 0; off >>= 1) s += __shfl_down(s, off, 64);
    if (lane == 0) red[w] = s;
    __syncthreads();
    if (tid == 0) {
        float tsum = 0.0f;
        for (int i = 0; i < 8; ++i) tsum += red[i];
        stats[0] = tsum * (1.0f / 6464.0f);
    }
    __syncthreads();
    const float mu = stats[0];
    float v = 0.0f;
    for (int i = tid; i < 6464; i += BLOCK) { float d = fbuf[i] - mu; v = fmaf(d, d, v); }
    #pragma unroll
    for (int off = 32; off > 0; off >>= 1) v += __shfl_down(v, off, 64);
    if (lane == 0) red[w] = v;
    __syncthreads();
    if (tid == 0) {
        float tsum = 0.0f;
        for (int i = 0; i < 8; ++i) tsum += red[i];
        stats[1] = tsum * (1.0f / 6464.0f);
    }
    __syncthreads();
    const float var  = stats[1];
    const float isig = 1.0f / sqrtf(var + 1e-5f);

    for (int idx = tid; idx < 4096; idx += BLOCK) {
        const int to = idx >> 6;
        const int c  = idx & 63;
        float pos = ((float)to + 0.5f) * 1.578125f - 0.5f;
        pos = fminf(fmaxf(pos, 0.0f), 100.0f);
        int i0 = (int)floorf(pos);
        int i1 = i0 + 1; if (i1 > 100) i1 = 100;
        float fr = pos - (float)i0;
        float wc = ln_w[c], bc = ln_b[c];
        float x0 = fbuf[c * 101 + i0];
        float x1 = fbuf[c * 101 + i1];
        float y0 = fmaf(wc, (x0 - mu) * isig, bc);
        float y1 = fmaf(wc, (x1 - mu) * isig, bc);
        float l0 = log10f(fmaf(y0, y0, 1e-6f));
        float l1 = log10f(fmaf(y1, y1, 1e-6f));
        out[b * 4096 + idx] = l0 * (1.0f - fr) + l1 * fr;
    }
}

extern "C" void kernel_launch(void* const* d_in, const int* in_sizes, int n_in,
                              void* d_out, int out_size, void* d_ws, size_t ws_size,
                              hipStream_t stream)
{
    const float* wav = (const float*)d_in[0];
    const float* lo  = (const float*)d_in[1];
    const float* bd  = (const float*)d_in[2];
    const float* lw  = (const float*)d_in[3];
    const float* lb  = (const float*)d_in[4];
    float* out = (float*)d_out;

    fse_filters<<<(64 * 201 + 255) / 256, 256, 0, stream>>>(lo, bd, out + 1024 * 4096);

    const size_t BNEED = (size_t)372736 * sizeof(unsigned short); // 745472 B
    if (ws_size >= BNEED) {
        unsigned short* Bts = (unsigned short*)d_ws;
        fse_setup_B<<<(372736 + 255) / 256, 256, 0, stream>>>(Bts);
        fse_main_mfma<<<1024, BLOCK, 0, stream>>>(wav, lo, bd, lw, lb, Bts, out);
    } else {
        fse_main_valu<<<1024, BLOCK, 0, stream>>>(wav, lo, bd, lw, lb, out);
    }
}